// Round 4
// baseline (816.499 us; speedup 1.0000x reference)
//
#include <hip/hip_runtime.h>
#include <math.h>

#define N_NODES 100000
#define N_EDGES 3200000
#define D_IN    256
#define D_OUT   128
#define ALPHA   0.2f

// round-to-nearest-even f32 -> bf16
__device__ __forceinline__ unsigned int f2bf(float x) {
    unsigned int u = __float_as_uint(x);
    return (u + 0x7fffu + ((u >> 16) & 1u)) >> 16;
}
__device__ __forceinline__ unsigned int packbf(float lo, float hi) {
    return f2bf(lo) | (f2bf(hi) << 16);
}
__device__ __forceinline__ float bflo(unsigned int v) { return __uint_as_float(v << 16); }
__device__ __forceinline__ float bfhi(unsigned int v) { return __uint_as_float(v & 0xffff0000u); }

// ---------- init: zero degree counters (ws re-poisoned to 0xAA every launch) ----------
__global__ void init_kernel(unsigned int* __restrict__ cnt) {
    int i = blockIdx.x * 256 + threadIdx.x;
    if (i < N_NODES) cnt[i] = 0u;
}

// ---------- GEMM: seq = feat @ W (f32 VALU) + fused f1/f2 epilogue ----------
// Block: 256 thr, 32 nodes/block. Thread = (jt -> 4 cols, g -> 4 nodes).
// Inner loop k-blocked x4: ds_read_b128 feat (wave-broadcast) + float4 W loads
// per 64 FMAs.
__global__ __launch_bounds__(256) void gemm_kernel(const float* __restrict__ feat,
                                                   const float* __restrict__ W,
                                                   const float* __restrict__ al_w,
                                                   const float* __restrict__ al_b,
                                                   const float* __restrict__ ar_w,
                                                   const float* __restrict__ ar_b,
                                                   unsigned int* __restrict__ seqb,
                                                   float* __restrict__ f1,
                                                   float* __restrict__ f2) {
    __shared__ float ldsF[32 * D_IN];   // 32 KB
    const int tid  = threadIdx.x;
    const int base = blockIdx.x * 32;

    const float4* ff4 = (const float4*)(feat + (size_t)base * D_IN);
    float4* l4 = (float4*)ldsF;
#pragma unroll
    for (int i = 0; i < 8; i++) l4[tid + i * 256] = ff4[tid + i * 256];
    __syncthreads();

    const int jt = tid & 31;   // cols jt*4 .. jt*4+3
    const int g  = tid >> 5;   // nodes g*4 .. g*4+3
    const float4* fp4 = (const float4*)(ldsF + g * 4 * D_IN);
    const float4* W4  = (const float4*)W;

    float acc[4][4] = {{0.f}};
    for (int k = 0; k < D_IN; k += 4) {
        float4 w0 = W4[(k + 0) * 32 + jt];
        float4 w1 = W4[(k + 1) * 32 + jt];
        float4 w2 = W4[(k + 2) * 32 + jt];
        float4 w3 = W4[(k + 3) * 32 + jt];
#pragma unroll
        for (int n = 0; n < 4; n++) {
            float4 a = fp4[n * (D_IN / 4) + (k >> 2)];   // ds_read_b128, wave-broadcast
            acc[n][0] += a.x * w0.x + a.y * w1.x + a.z * w2.x + a.w * w3.x;
            acc[n][1] += a.x * w0.y + a.y * w1.y + a.z * w2.y + a.w * w3.y;
            acc[n][2] += a.x * w0.z + a.y * w1.z + a.z * w2.z + a.w * w3.z;
            acc[n][3] += a.x * w0.w + a.y * w1.w + a.z * w2.w + a.w * w3.w;
        }
    }

    const float4 al4 = ((const float4*)al_w)[jt];
    const float4 ar4 = ((const float4*)ar_w)[jt];
    const float alb = al_b[0], arb = ar_b[0];

#pragma unroll
    for (int n = 0; n < 4; n++) {
        int node = base + g * 4 + n;
        uint2 pv = make_uint2(packbf(acc[n][0], acc[n][1]), packbf(acc[n][2], acc[n][3]));
        ((uint2*)(seqb + (size_t)node * 64))[jt] = pv;
        float p1 = acc[n][0] * al4.x + acc[n][1] * al4.y + acc[n][2] * al4.z + acc[n][3] * al4.w;
        float p2 = acc[n][0] * ar4.x + acc[n][1] * ar4.y + acc[n][2] * ar4.z + acc[n][3] * ar4.w;
#pragma unroll
        for (int m = 16; m > 0; m >>= 1) {
            p1 += __shfl_xor(p1, m);
            p2 += __shfl_xor(p2, m);
        }
        if (jt == 0) {
            f1[node] = p1 + alb;
            f2[node] = p2 + arb;
        }
    }
}

// ---------- edge pass 1: degree histogram (segment-max skipped: softmax is ----------
// shift-invariant; logits are O(sigma=~1.4) so f32 exp cannot overflow)
__global__ __launch_bounds__(256) void edge_hist(const int4* __restrict__ row4,
                                                 unsigned int* __restrict__ cnt) {
    int i = blockIdx.x * 256 + threadIdx.x;   // over E/4
    int4 r = row4[i];
    atomicAdd(&cnt[r.x], 1u);
    atomicAdd(&cnt[r.y], 1u);
    atomicAdd(&cnt[r.z], 1u);
    atomicAdd(&cnt[r.w], 1u);
}

// ---------- exclusive scan of degrees -> CSR row offsets ----------
__global__ void scan1(const unsigned int* __restrict__ cnt,
                      unsigned int* __restrict__ offs,
                      unsigned int* __restrict__ bsums) {
    __shared__ unsigned int s[256];
    int t = threadIdx.x;
    int i = blockIdx.x * 256 + t;
    unsigned int v = (i < N_NODES) ? cnt[i] : 0u;
    s[t] = v; __syncthreads();
    for (int d = 1; d < 256; d <<= 1) {
        unsigned int x = (t >= d) ? s[t - d] : 0u;
        __syncthreads();
        s[t] += x;
        __syncthreads();
    }
    if (i < N_NODES) offs[i] = s[t] - v;
    if (t == 255) bsums[blockIdx.x] = s[255];
}

__global__ void scan2(const unsigned int* __restrict__ bsums,
                      unsigned int* __restrict__ bexcl, int nb) {
    __shared__ unsigned int s[512];
    int t = threadIdx.x;
    unsigned int v = (t < nb) ? bsums[t] : 0u;
    s[t] = v; __syncthreads();
    for (int d = 1; d < 512; d <<= 1) {
        unsigned int x = (t >= d) ? s[t - d] : 0u;
        __syncthreads();
        s[t] += x;
        __syncthreads();
    }
    if (t < nb) bexcl[t] = s[t] - v;
}

// adds block prefix AND initializes cursor = offs so edge_pass2's atomic
// returns the absolute CSR position directly (no offs gather in its chain)
__global__ void scan3(unsigned int* __restrict__ offs,
                      const unsigned int* __restrict__ bexcl,
                      unsigned int* __restrict__ cursor) {
    int i = blockIdx.x * 256 + threadIdx.x;
    if (i < N_NODES) {
        unsigned int o = offs[i] + bexcl[blockIdx.x];
        offs[i] = o;
        cursor[i] = o;
    }
}

// ---------- edge pass 2: CSR scatter of col (4B), 4 edges/thread ----------
// 4 independent atomic->store chains per thread hide the ~300cy L2 RMW latency
// (R3 post-mortem: MLP=1 made this kernel latency-bound at 14% BW).
__global__ __launch_bounds__(256) void edge_pass2(const int4* __restrict__ row4,
                                                  const int4* __restrict__ col4,
                                                  unsigned int* __restrict__ cursor,
                                                  int* __restrict__ sorted_c) {
    int i = blockIdx.x * 256 + threadIdx.x;   // over E/4
    int4 r = row4[i];
    int4 c = col4[i];
    unsigned int p0 = atomicAdd(&cursor[r.x], 1u);
    unsigned int p1 = atomicAdd(&cursor[r.y], 1u);
    unsigned int p2 = atomicAdd(&cursor[r.z], 1u);
    unsigned int p3 = atomicAdd(&cursor[r.w], 1u);
    sorted_c[p0] = c.x;
    sorted_c[p1] = c.y;
    sorted_c[p2] = c.z;
    sorted_c[p3] = c.w;
}

// ---------- row aggregate ----------
// One wave per row, split into two 32-lane halves; each half owns one edge per
// step (lane j2 = lane&31 holds cols 4*j2..4*j2+3 via one uint2 = 8B load).
// Unroll x4 -> 8 edges / wave-step, 4 outstanding 8B gathers per lane.
// Halves combined at the end with __shfl_xor(...,32).
__global__ __launch_bounds__(256) void row_kernel(const uint2* __restrict__ seqb2,
                                                  const int* __restrict__ sorted_c,
                                                  const unsigned int* __restrict__ offs,
                                                  const unsigned int* __restrict__ cnt,
                                                  const float* __restrict__ f1,
                                                  const float* __restrict__ f2,
                                                  const float* __restrict__ bias,
                                                  float* __restrict__ out) {
    int wid  = (blockIdx.x * 256 + threadIdx.x) >> 6;   // row
    int lane = threadIdx.x & 63;
    int half = lane >> 5;
    int j2   = lane & 31;       // cols 4*j2 .. 4*j2+3
    if (wid >= N_NODES) return;
    unsigned int start = offs[wid];
    unsigned int deg   = cnt[wid];
    const int* sc = sorted_c + start;
    float f1r = f1[wid];

    float a0 = 0.f, a1 = 0.f, a2 = 0.f, a3 = 0.f, ss = 0.f;
    unsigned int k = 0;
    for (; k + 8 <= deg; k += 8) {
        int c0 = sc[k + 0 + half];
        int c1 = sc[k + 2 + half];
        int c2 = sc[k + 4 + half];
        int c3 = sc[k + 6 + half];
        uint2 v0 = seqb2[(size_t)c0 * 32 + j2];
        uint2 v1 = seqb2[(size_t)c1 * 32 + j2];
        uint2 v2 = seqb2[(size_t)c2 * 32 + j2];
        uint2 v3 = seqb2[(size_t)c3 * 32 + j2];
        float t0 = f1r + f2[c0], t1 = f1r + f2[c1];
        float t2 = f1r + f2[c2], t3 = f1r + f2[c3];
        float w0 = __expf(t0 > 0.f ? t0 : ALPHA * t0);
        float w1 = __expf(t1 > 0.f ? t1 : ALPHA * t1);
        float w2 = __expf(t2 > 0.f ? t2 : ALPHA * t2);
        float w3 = __expf(t3 > 0.f ? t3 : ALPHA * t3);
        a0 += w0 * bflo(v0.x); a1 += w0 * bfhi(v0.x); a2 += w0 * bflo(v0.y); a3 += w0 * bfhi(v0.y);
        a0 += w1 * bflo(v1.x); a1 += w1 * bfhi(v1.x); a2 += w1 * bflo(v1.y); a3 += w1 * bfhi(v1.y);
        a0 += w2 * bflo(v2.x); a1 += w2 * bfhi(v2.x); a2 += w2 * bflo(v2.y); a3 += w2 * bfhi(v2.y);
        a0 += w3 * bflo(v3.x); a1 += w3 * bfhi(v3.x); a2 += w3 * bflo(v3.y); a3 += w3 * bfhi(v3.y);
        ss += w0 + w1 + w2 + w3;
    }
    for (; k + 2 <= deg; k += 2) {       // pairs: one edge per half
        int c0 = sc[k + half];
        uint2 v0 = seqb2[(size_t)c0 * 32 + j2];
        float t0 = f1r + f2[c0];
        float w0 = __expf(t0 > 0.f ? t0 : ALPHA * t0);
        a0 += w0 * bflo(v0.x); a1 += w0 * bfhi(v0.x); a2 += w0 * bflo(v0.y); a3 += w0 * bfhi(v0.y);
        ss += w0;
    }
    if (k < deg && half == 0) {          // final odd edge: half 0 only
        int c0 = sc[k];
        uint2 v0 = seqb2[(size_t)c0 * 32 + j2];
        float t0 = f1r + f2[c0];
        float w0 = __expf(t0 > 0.f ? t0 : ALPHA * t0);
        a0 += w0 * bflo(v0.x); a1 += w0 * bfhi(v0.x); a2 += w0 * bflo(v0.y); a3 += w0 * bfhi(v0.y);
        ss += w0;
    }
    // combine halves (after this every lane holds the full sums)
    a0 += __shfl_xor(a0, 32);
    a1 += __shfl_xor(a1, 32);
    a2 += __shfl_xor(a2, 32);
    a3 += __shfl_xor(a3, 32);
    ss += __shfl_xor(ss, 32);

    if (half == 0) {
        float inv = (deg > 0) ? 1.f / ss : 0.f;   // empty row -> bias only
        float4 b4 = ((const float4*)bias)[j2];
        ((float4*)(out + (size_t)wid * D_OUT))[j2] =
            make_float4(a0 * inv + b4.x, a1 * inv + b4.y, a2 * inv + b4.z, a3 * inv + b4.w);
    }
}

extern "C" void kernel_launch(void* const* d_in, const int* in_sizes, int n_in,
                              void* d_out, int out_size, void* d_ws, size_t ws_size,
                              hipStream_t stream) {
    const float* feat = (const float*)d_in[0];
    const int*   row  = (const int*)d_in[1];
    const int*   col  = (const int*)d_in[2];
    const float* W    = (const float*)d_in[3];
    const float* al_w = (const float*)d_in[4];
    const float* al_b = (const float*)d_in[5];
    const float* ar_w = (const float*)d_in[6];
    const float* ar_b = (const float*)d_in[7];
    const float* bias = (const float*)d_in[8];
    float* out = (float*)d_out;

    char* ws = (char*)d_ws;
    size_t off = 0;
    auto carve = [&](size_t bytes) -> void* {
        off = (off + 255) & ~(size_t)255;
        void* p = ws + off;
        off += bytes;
        return p;
    };
    unsigned int* seqb     = (unsigned int*)carve((size_t)N_NODES * 64 * 4);  // bf16x2 packed
    float*        f1       = (float*)       carve((size_t)N_NODES * 4);
    float*        f2       = (float*)       carve((size_t)N_NODES * 4);
    unsigned int* cnt      = (unsigned int*)carve((size_t)N_NODES * 4);
    unsigned int* offs     = (unsigned int*)carve((size_t)N_NODES * 4);
    unsigned int* cursor   = (unsigned int*)carve((size_t)N_NODES * 4);
    unsigned int* bsums    = (unsigned int*)carve(1024 * 4);
    unsigned int* bexcl    = (unsigned int*)carve(1024 * 4);
    int*          sorted_c = (int*)         carve((size_t)N_EDGES * 4);
    (void)ws_size; (void)in_sizes; (void)n_in; (void)out_size;

    const int nb_nodes = (N_NODES + 255) / 256;   // 391
    const int nb_gemm  = N_NODES / 32;            // 3125 exact
    const int nb_e4    = (N_EDGES / 4) / 256;     // 3125 exact
    const int nb_row   = N_NODES / 4;             // 25000 exact (4 waves/block)

    init_kernel<<<nb_nodes, 256, 0, stream>>>(cnt);
    gemm_kernel<<<nb_gemm, 256, 0, stream>>>(feat, W, al_w, al_b, ar_w, ar_b, seqb, f1, f2);
    edge_hist<<<nb_e4, 256, 0, stream>>>((const int4*)row, cnt);
    scan1<<<nb_nodes, 256, 0, stream>>>(cnt, offs, bsums);
    scan2<<<1, 512, 0, stream>>>(bsums, bexcl, nb_nodes);
    scan3<<<nb_nodes, 256, 0, stream>>>(offs, bexcl, cursor);
    edge_pass2<<<nb_e4, 256, 0, stream>>>((const int4*)row, (const int4*)col, cursor, sorted_c);
    row_kernel<<<nb_row, 256, 0, stream>>>((const uint2*)seqb, sorted_c, offs, cnt, f1, f2, bias, out);
}

// Round 5
// 616.189 us; speedup vs baseline: 1.3251x; 1.3251x over previous
//
#include <hip/hip_runtime.h>
#include <math.h>

#define N_NODES 100000
#define N_EDGES 3200000
#define D_IN    256
#define D_OUT   128
#define ALPHA   0.2f
#define NSEG     8        // row-range segments == XCD count
#define SEG_SIZE 12500    // N_NODES / NSEG

// round-to-nearest-even f32 -> bf16
__device__ __forceinline__ unsigned int f2bf(float x) {
    unsigned int u = __float_as_uint(x);
    return (u + 0x7fffu + ((u >> 16) & 1u)) >> 16;
}
__device__ __forceinline__ unsigned int packbf(float lo, float hi) {
    return f2bf(lo) | (f2bf(hi) << 16);
}
__device__ __forceinline__ float bflo(unsigned int v) { return __uint_as_float(v << 16); }
__device__ __forceinline__ float bfhi(unsigned int v) { return __uint_as_float(v & 0xffff0000u); }

// ---------- init: zero degree counters (ws re-poisoned to 0xAA every launch) ----------
__global__ void init_kernel(unsigned int* __restrict__ cnt) {
    int i = blockIdx.x * 256 + threadIdx.x;
    if (i < N_NODES) cnt[i] = 0u;
}

// ---------- GEMM: seq = feat @ W (f32 VALU) + fused f1/f2 epilogue ----------
__global__ __launch_bounds__(256) void gemm_kernel(const float* __restrict__ feat,
                                                   const float* __restrict__ W,
                                                   const float* __restrict__ al_w,
                                                   const float* __restrict__ al_b,
                                                   const float* __restrict__ ar_w,
                                                   const float* __restrict__ ar_b,
                                                   unsigned int* __restrict__ seqb,
                                                   float* __restrict__ f1,
                                                   float* __restrict__ f2) {
    __shared__ float ldsF[32 * D_IN];   // 32 KB
    const int tid  = threadIdx.x;
    const int base = blockIdx.x * 32;

    const float4* ff4 = (const float4*)(feat + (size_t)base * D_IN);
    float4* l4 = (float4*)ldsF;
#pragma unroll
    for (int i = 0; i < 8; i++) l4[tid + i * 256] = ff4[tid + i * 256];
    __syncthreads();

    const int jt = tid & 31;   // cols jt*4 .. jt*4+3
    const int g  = tid >> 5;   // nodes g*4 .. g*4+3
    const float4* fp4 = (const float4*)(ldsF + g * 4 * D_IN);
    const float4* W4  = (const float4*)W;

    float acc[4][4] = {{0.f}};
    for (int k = 0; k < D_IN; k += 4) {
        float4 w0 = W4[(k + 0) * 32 + jt];
        float4 w1 = W4[(k + 1) * 32 + jt];
        float4 w2 = W4[(k + 2) * 32 + jt];
        float4 w3 = W4[(k + 3) * 32 + jt];
#pragma unroll
        for (int n = 0; n < 4; n++) {
            float4 a = fp4[n * (D_IN / 4) + (k >> 2)];   // ds_read_b128, wave-broadcast
            acc[n][0] += a.x * w0.x + a.y * w1.x + a.z * w2.x + a.w * w3.x;
            acc[n][1] += a.x * w0.y + a.y * w1.y + a.z * w2.y + a.w * w3.y;
            acc[n][2] += a.x * w0.z + a.y * w1.z + a.z * w2.z + a.w * w3.z;
            acc[n][3] += a.x * w0.w + a.y * w1.w + a.z * w2.w + a.w * w3.w;
        }
    }

    const float4 al4 = ((const float4*)al_w)[jt];
    const float4 ar4 = ((const float4*)ar_w)[jt];
    const float alb = al_b[0], arb = ar_b[0];

#pragma unroll
    for (int n = 0; n < 4; n++) {
        int node = base + g * 4 + n;
        uint2 pv = make_uint2(packbf(acc[n][0], acc[n][1]), packbf(acc[n][2], acc[n][3]));
        ((uint2*)(seqb + (size_t)node * 64))[jt] = pv;
        float p1 = acc[n][0] * al4.x + acc[n][1] * al4.y + acc[n][2] * al4.z + acc[n][3] * al4.w;
        float p2 = acc[n][0] * ar4.x + acc[n][1] * ar4.y + acc[n][2] * ar4.z + acc[n][3] * ar4.w;
#pragma unroll
        for (int m = 16; m > 0; m >>= 1) {
            p1 += __shfl_xor(p1, m);
            p2 += __shfl_xor(p2, m);
        }
        if (jt == 0) {
            f1[node] = p1 + alb;
            f2[node] = p2 + arb;
        }
    }
}

// ---------- hist + rank: deg histogram AND each edge's within-row rank ----------
// rank[e] = atomicAdd(&cnt[row[e]],1) -- the scatter pass then needs NO atomic.
// Ranks packed uchar4 (deg ~ Poisson(32); P(deg>255) ~ e^-246). Store is one
// coalesced 4B write after all 4 atomics return (not 4 scattered stores - R4 lesson).
__global__ __launch_bounds__(256) void hist_rank(const int4* __restrict__ row4,
                                                 unsigned int* __restrict__ cnt,
                                                 uchar4* __restrict__ rank4) {
    int i = blockIdx.x * 256 + threadIdx.x;   // over E/4
    int4 r = row4[i];
    unsigned int k0 = atomicAdd(&cnt[r.x], 1u);
    unsigned int k1 = atomicAdd(&cnt[r.y], 1u);
    unsigned int k2 = atomicAdd(&cnt[r.z], 1u);
    unsigned int k3 = atomicAdd(&cnt[r.w], 1u);
    rank4[i] = make_uchar4((unsigned char)k0, (unsigned char)k1,
                           (unsigned char)k2, (unsigned char)k3);
}

// ---------- exclusive scan of degrees -> CSR row offsets ----------
__global__ void scan1(const unsigned int* __restrict__ cnt,
                      unsigned int* __restrict__ offs,
                      unsigned int* __restrict__ bsums) {
    __shared__ unsigned int s[256];
    int t = threadIdx.x;
    int i = blockIdx.x * 256 + t;
    unsigned int v = (i < N_NODES) ? cnt[i] : 0u;
    s[t] = v; __syncthreads();
    for (int d = 1; d < 256; d <<= 1) {
        unsigned int x = (t >= d) ? s[t - d] : 0u;
        __syncthreads();
        s[t] += x;
        __syncthreads();
    }
    if (i < N_NODES) offs[i] = s[t] - v;
    if (t == 255) bsums[blockIdx.x] = s[255];
}

__global__ void scan2(const unsigned int* __restrict__ bsums,
                      unsigned int* __restrict__ bexcl, int nb) {
    __shared__ unsigned int s[512];
    int t = threadIdx.x;
    unsigned int v = (t < nb) ? bsums[t] : 0u;
    s[t] = v; __syncthreads();
    for (int d = 1; d < 512; d <<= 1) {
        unsigned int x = (t >= d) ? s[t - d] : 0u;
        __syncthreads();
        s[t] += x;
        __syncthreads();
    }
    if (t < nb) bexcl[t] = s[t] - v;
}

__global__ void scan3(unsigned int* __restrict__ offs,
                      const unsigned int* __restrict__ bexcl) {
    int i = blockIdx.x * 256 + threadIdx.x;
    if (i < N_NODES) offs[i] += bexcl[blockIdx.x];
}

// ---------- XCD-localized CSR scatter (no atomics) ----------
// 8x blocks; block b handles edge chunk b>>3 but only rows in segment b&7
// (12.5k rows = 1.6MB slice of sorted_c). With round-robin block->XCD dispatch,
// segment g is written only from XCD g -> slice stays L2-resident, 64B lines
// collect all ~16 entries before one eviction (kills the 195MB write blowup).
__global__ __launch_bounds__(256) void scatter_kernel(const int* __restrict__ row,
                                                      const int* __restrict__ col,
                                                      const unsigned char* __restrict__ rank,
                                                      const unsigned int* __restrict__ offs,
                                                      int* __restrict__ sorted_c) {
    int seg   = blockIdx.x & 7;
    int chunk = blockIdx.x >> 3;
    int e = chunk * 256 + threadIdx.x;
    int r = row[e];
    unsigned int rel = (unsigned int)(r - seg * SEG_SIZE);
    if (rel < (unsigned int)SEG_SIZE) {
        unsigned int p = offs[r] + (unsigned int)rank[e];
        sorted_c[p] = col[e];
    }
}

// ---------- row aggregate ----------
// One wave per row, two 32-lane halves; lane j2 holds cols 4*j2..4*j2+3 via one
// uint2 (8B) load; unroll x4 -> 8 edges in flight per wave.
__global__ __launch_bounds__(256) void row_kernel(const uint2* __restrict__ seqb2,
                                                  const int* __restrict__ sorted_c,
                                                  const unsigned int* __restrict__ offs,
                                                  const unsigned int* __restrict__ cnt,
                                                  const float* __restrict__ f1,
                                                  const float* __restrict__ f2,
                                                  const float* __restrict__ bias,
                                                  float* __restrict__ out) {
    int wid  = (blockIdx.x * 256 + threadIdx.x) >> 6;   // row
    int lane = threadIdx.x & 63;
    int half = lane >> 5;
    int j2   = lane & 31;       // cols 4*j2 .. 4*j2+3
    if (wid >= N_NODES) return;
    unsigned int start = offs[wid];
    unsigned int deg   = cnt[wid];
    const int* sc = sorted_c + start;
    float f1r = f1[wid];

    float a0 = 0.f, a1 = 0.f, a2 = 0.f, a3 = 0.f, ss = 0.f;
    unsigned int k = 0;
    for (; k + 8 <= deg; k += 8) {
        int c0 = sc[k + 0 + half];
        int c1 = sc[k + 2 + half];
        int c2 = sc[k + 4 + half];
        int c3 = sc[k + 6 + half];
        uint2 v0 = seqb2[(size_t)c0 * 32 + j2];
        uint2 v1 = seqb2[(size_t)c1 * 32 + j2];
        uint2 v2 = seqb2[(size_t)c2 * 32 + j2];
        uint2 v3 = seqb2[(size_t)c3 * 32 + j2];
        float t0 = f1r + f2[c0], t1 = f1r + f2[c1];
        float t2 = f1r + f2[c2], t3 = f1r + f2[c3];
        float w0 = __expf(t0 > 0.f ? t0 : ALPHA * t0);
        float w1 = __expf(t1 > 0.f ? t1 : ALPHA * t1);
        float w2 = __expf(t2 > 0.f ? t2 : ALPHA * t2);
        float w3 = __expf(t3 > 0.f ? t3 : ALPHA * t3);
        a0 += w0 * bflo(v0.x); a1 += w0 * bfhi(v0.x); a2 += w0 * bflo(v0.y); a3 += w0 * bfhi(v0.y);
        a0 += w1 * bflo(v1.x); a1 += w1 * bfhi(v1.x); a2 += w1 * bflo(v1.y); a3 += w1 * bfhi(v1.y);
        a0 += w2 * bflo(v2.x); a1 += w2 * bfhi(v2.x); a2 += w2 * bflo(v2.y); a3 += w2 * bfhi(v2.y);
        a0 += w3 * bflo(v3.x); a1 += w3 * bfhi(v3.x); a2 += w3 * bflo(v3.y); a3 += w3 * bfhi(v3.y);
        ss += w0 + w1 + w2 + w3;
    }
    for (; k + 2 <= deg; k += 2) {       // pairs: one edge per half
        int c0 = sc[k + half];
        uint2 v0 = seqb2[(size_t)c0 * 32 + j2];
        float t0 = f1r + f2[c0];
        float w0 = __expf(t0 > 0.f ? t0 : ALPHA * t0);
        a0 += w0 * bflo(v0.x); a1 += w0 * bfhi(v0.x); a2 += w0 * bflo(v0.y); a3 += w0 * bfhi(v0.y);
        ss += w0;
    }
    if (k < deg && half == 0) {          // final odd edge: half 0 only
        int c0 = sc[k];
        uint2 v0 = seqb2[(size_t)c0 * 32 + j2];
        float t0 = f1r + f2[c0];
        float w0 = __expf(t0 > 0.f ? t0 : ALPHA * t0);
        a0 += w0 * bflo(v0.x); a1 += w0 * bfhi(v0.x); a2 += w0 * bflo(v0.y); a3 += w0 * bfhi(v0.y);
        ss += w0;
    }
    a0 += __shfl_xor(a0, 32);
    a1 += __shfl_xor(a1, 32);
    a2 += __shfl_xor(a2, 32);
    a3 += __shfl_xor(a3, 32);
    ss += __shfl_xor(ss, 32);

    if (half == 0) {
        float inv = (deg > 0) ? 1.f / ss : 0.f;   // empty row -> bias only
        float4 b4 = ((const float4*)bias)[j2];
        ((float4*)(out + (size_t)wid * D_OUT))[j2] =
            make_float4(a0 * inv + b4.x, a1 * inv + b4.y, a2 * inv + b4.z, a3 * inv + b4.w);
    }
}

extern "C" void kernel_launch(void* const* d_in, const int* in_sizes, int n_in,
                              void* d_out, int out_size, void* d_ws, size_t ws_size,
                              hipStream_t stream) {
    const float* feat = (const float*)d_in[0];
    const int*   row  = (const int*)d_in[1];
    const int*   col  = (const int*)d_in[2];
    const float* W    = (const float*)d_in[3];
    const float* al_w = (const float*)d_in[4];
    const float* al_b = (const float*)d_in[5];
    const float* ar_w = (const float*)d_in[6];
    const float* ar_b = (const float*)d_in[7];
    const float* bias = (const float*)d_in[8];
    float* out = (float*)d_out;

    char* ws = (char*)d_ws;
    size_t off = 0;
    auto carve = [&](size_t bytes) -> void* {
        off = (off + 255) & ~(size_t)255;
        void* p = ws + off;
        off += bytes;
        return p;
    };
    unsigned int* seqb     = (unsigned int*)carve((size_t)N_NODES * 64 * 4);  // bf16x2 packed
    float*        f1       = (float*)       carve((size_t)N_NODES * 4);
    float*        f2       = (float*)       carve((size_t)N_NODES * 4);
    unsigned int* cnt      = (unsigned int*)carve((size_t)N_NODES * 4);
    unsigned int* offs     = (unsigned int*)carve((size_t)N_NODES * 4);
    unsigned int* bsums    = (unsigned int*)carve(1024 * 4);
    unsigned int* bexcl    = (unsigned int*)carve(1024 * 4);
    unsigned char* rank    = (unsigned char*)carve((size_t)N_EDGES);
    int*          sorted_c = (int*)         carve((size_t)N_EDGES * 4);
    (void)ws_size; (void)in_sizes; (void)n_in; (void)out_size;

    const int nb_nodes = (N_NODES + 255) / 256;   // 391
    const int nb_gemm  = N_NODES / 32;            // 3125 exact
    const int nb_e4    = (N_EDGES / 4) / 256;     // 3125 exact
    const int nb_scat  = (N_EDGES / 256) * NSEG;  // 100000
    const int nb_row   = N_NODES / 4;             // 25000 exact (4 waves/block)

    init_kernel<<<nb_nodes, 256, 0, stream>>>(cnt);
    gemm_kernel<<<nb_gemm, 256, 0, stream>>>(feat, W, al_w, al_b, ar_w, ar_b, seqb, f1, f2);
    hist_rank<<<nb_e4, 256, 0, stream>>>((const int4*)row, cnt, (uchar4*)rank);
    scan1<<<nb_nodes, 256, 0, stream>>>(cnt, offs, bsums);
    scan2<<<1, 512, 0, stream>>>(bsums, bexcl, nb_nodes);
    scan3<<<nb_nodes, 256, 0, stream>>>(offs, bexcl);
    scatter_kernel<<<nb_scat, 256, 0, stream>>>(row, col, rank, offs, sorted_c);
    row_kernel<<<nb_row, 256, 0, stream>>>((const uint2*)seqb, sorted_c, offs, cnt, f1, f2, bias, out);
}

// Round 6
// 564.541 us; speedup vs baseline: 1.4463x; 1.0915x over previous
//
#include <hip/hip_runtime.h>
#include <math.h>

#define N_NODES 100000
#define N_EDGES 3200000
#define D_IN    256
#define D_OUT   128
#define ALPHA   0.2f
#define NSEG     8        // row-range segments == XCD count
#define SEG_SIZE 12500    // N_NODES / NSEG

typedef short bf8_t  __attribute__((ext_vector_type(8)));   // 8 bf16 (MFMA A/B frag)
typedef float f4_t   __attribute__((ext_vector_type(4)));   // 4 f32  (MFMA C/D frag)

// round-to-nearest-even f32 -> bf16
__device__ __forceinline__ unsigned int f2bf(float x) {
    unsigned int u = __float_as_uint(x);
    return (u + 0x7fffu + ((u >> 16) & 1u)) >> 16;
}
__device__ __forceinline__ unsigned int packbf(float lo, float hi) {
    return f2bf(lo) | (f2bf(hi) << 16);
}
__device__ __forceinline__ float bflo(unsigned int v) { return __uint_as_float(v << 16); }
__device__ __forceinline__ float bfhi(unsigned int v) { return __uint_as_float(v & 0xffff0000u); }

// ---------- init: zero degree counters (ws re-poisoned to 0xAA every launch) ----------
__global__ void init_kernel(unsigned int* __restrict__ cnt) {
    int i = blockIdx.x * 256 + threadIdx.x;
    if (i < N_NODES) cnt[i] = 0u;
}

// ---------- WT: W[k][n] f32 -> WT[n][k] bf16 (64 KB, done once per launch) ----------
__global__ void wt_kernel(const float* __restrict__ W, short* __restrict__ WT) {
    int i = blockIdx.x * 256 + threadIdx.x;   // 32768
    int n = i >> 8, k = i & 255;
    WT[i] = (short)f2bf(W[k * 128 + n]);
}

// ---------- GEMM via bf16 MFMA: seq = feat @ W + fused f1/f2 epilogue ----------
// Block: 256 thr = 4 waves; wave handles 16 rows x 128 cols. Block = 64 rows.
// feat tile staged f32->bf16 into LDS ([64][264] shorts, +16B row pad -> fragment
// reads are bank-bandwidth-optimal). B-frags read straight from global WT (16B
// contiguous per lane, L1/L2-resident 64 KB). mfma_f32_16x16x32_bf16:
//   A[m=lane&15][k=quad*8+j], B[k=quad*8+j][n=lane&15], C col=lane&15 row=quad*4+reg.
__global__ __launch_bounds__(256) void gemm_kernel(const float* __restrict__ feat,
                                                   const short* __restrict__ WT,
                                                   const float* __restrict__ al_w,
                                                   const float* __restrict__ al_b,
                                                   const float* __restrict__ ar_w,
                                                   const float* __restrict__ ar_b,
                                                   unsigned int* __restrict__ seqb,
                                                   float* __restrict__ f1,
                                                   float* __restrict__ f2) {
    __shared__ char ldsA[64 * 528];   // 33.8 KB  (row stride 528 B = 264 bf16)
    const int tid = threadIdx.x;
    const int tb  = blockIdx.x * 64;

    // ---- stage feat[tb..tb+63][0..255] as bf16 (clamp rows past N; stores guarded) ----
#pragma unroll
    for (int i = 0; i < 16; i++) {
        int idx = i * 256 + tid;          // over 4096 float4
        int r   = idx >> 6;               // tile row 0..63
        int c4  = idx & 63;               // float4 index 0..63
        int gr  = tb + r; if (gr >= N_NODES) gr = N_NODES - 1;
        float4 v = ((const float4*)feat)[(size_t)gr * 64 + c4];
        *(uint2*)(ldsA + r * 528 + c4 * 8) =
            make_uint2(packbf(v.x, v.y), packbf(v.z, v.w));
    }
    __syncthreads();

    const int w    = tid >> 6;      // wave 0..3 -> rows tb + w*16 ..
    const int lane = tid & 63;
    const int m    = lane & 15;     // A row / B col within tile
    const int q    = lane >> 4;     // quad -> k offset q*8, C rows q*4..q*4+3

    const char*  aptr  = ldsA + (w * 16 + m) * 528 + q * 16;
    const short* bbase = WT + m * 256 + q * 8;   // + nt*16*256 + kc*32

    f4_t acc[8];
#pragma unroll
    for (int nt = 0; nt < 8; nt++) acc[nt] = (f4_t)(0.f);

#pragma unroll
    for (int kc = 0; kc < 8; kc++) {
        bf8_t a = *(const bf8_t*)(aptr + kc * 64);
#pragma unroll
        for (int nt = 0; nt < 8; nt++) {
            bf8_t b = *(const bf8_t*)(bbase + nt * 4096 + kc * 32);
            acc[nt] = __builtin_amdgcn_mfma_f32_16x16x32_bf16(a, b, acc[nt], 0, 0, 0);
        }
    }

    // ---- epilogue 1: seqb packed bf16x2 (pair adjacent cols via shfl_xor(1)) ----
    const int node_base = tb + w * 16 + q * 4;
#pragma unroll
    for (int nt = 0; nt < 8; nt++) {
#pragma unroll
        for (int j = 0; j < 4; j++) {
            float own   = acc[nt][j];
            float other = __shfl_xor(own, 1);
            int node = node_base + j;
            if (!(lane & 1) && node < N_NODES)
                seqb[(size_t)node * 64 + nt * 8 + (m >> 1)] = packbf(own, other);
        }
    }

    // ---- epilogue 2: f1/f2 = seq . al_w / ar_w (reduce over cols = lanes m) ----
    float p1[4] = {0.f, 0.f, 0.f, 0.f}, p2[4] = {0.f, 0.f, 0.f, 0.f};
#pragma unroll
    for (int nt = 0; nt < 8; nt++) {
        float av = al_w[nt * 16 + m];
        float rv = ar_w[nt * 16 + m];
#pragma unroll
        for (int j = 0; j < 4; j++) {
            p1[j] += acc[nt][j] * av;
            p2[j] += acc[nt][j] * rv;
        }
    }
#pragma unroll
    for (int j = 0; j < 4; j++) {
#pragma unroll
        for (int mk = 1; mk < 16; mk <<= 1) {
            p1[j] += __shfl_xor(p1[j], mk);
            p2[j] += __shfl_xor(p2[j], mk);
        }
    }
    if (m == 0) {
        float alb = al_b[0], arb = ar_b[0];
#pragma unroll
        for (int j = 0; j < 4; j++) {
            int node = node_base + j;
            if (node < N_NODES) {
                f1[node] = p1[j] + alb;
                f2[node] = p2[j] + arb;
            }
        }
    }
}

// ---------- hist + rank: deg histogram AND each edge's within-row rank ----------
__global__ __launch_bounds__(256) void hist_rank(const int4* __restrict__ row4,
                                                 unsigned int* __restrict__ cnt,
                                                 uchar4* __restrict__ rank4) {
    int i = blockIdx.x * 256 + threadIdx.x;   // over E/4
    int4 r = row4[i];
    unsigned int k0 = atomicAdd(&cnt[r.x], 1u);
    unsigned int k1 = atomicAdd(&cnt[r.y], 1u);
    unsigned int k2 = atomicAdd(&cnt[r.z], 1u);
    unsigned int k3 = atomicAdd(&cnt[r.w], 1u);
    rank4[i] = make_uchar4((unsigned char)k0, (unsigned char)k1,
                           (unsigned char)k2, (unsigned char)k3);
}

// ---------- exclusive scan of degrees -> CSR row offsets ----------
__global__ void scan1(const unsigned int* __restrict__ cnt,
                      unsigned int* __restrict__ offs,
                      unsigned int* __restrict__ bsums) {
    __shared__ unsigned int s[256];
    int t = threadIdx.x;
    int i = blockIdx.x * 256 + t;
    unsigned int v = (i < N_NODES) ? cnt[i] : 0u;
    s[t] = v; __syncthreads();
    for (int d = 1; d < 256; d <<= 1) {
        unsigned int x = (t >= d) ? s[t - d] : 0u;
        __syncthreads();
        s[t] += x;
        __syncthreads();
    }
    if (i < N_NODES) offs[i] = s[t] - v;
    if (t == 255) bsums[blockIdx.x] = s[255];
}

__global__ void scan2(const unsigned int* __restrict__ bsums,
                      unsigned int* __restrict__ bexcl, int nb) {
    __shared__ unsigned int s[512];
    int t = threadIdx.x;
    unsigned int v = (t < nb) ? bsums[t] : 0u;
    s[t] = v; __syncthreads();
    for (int d = 1; d < 512; d <<= 1) {
        unsigned int x = (t >= d) ? s[t - d] : 0u;
        __syncthreads();
        s[t] += x;
        __syncthreads();
    }
    if (t < nb) bexcl[t] = s[t] - v;
}

__global__ void scan3(unsigned int* __restrict__ offs,
                      const unsigned int* __restrict__ bexcl) {
    int i = blockIdx.x * 256 + threadIdx.x;
    if (i < N_NODES) offs[i] += bexcl[blockIdx.x];
}

// ---------- XCD-localized CSR scatter (no atomics) ----------
__global__ __launch_bounds__(256) void scatter_kernel(const int* __restrict__ row,
                                                      const int* __restrict__ col,
                                                      const unsigned char* __restrict__ rank,
                                                      const unsigned int* __restrict__ offs,
                                                      int* __restrict__ sorted_c) {
    int seg   = blockIdx.x & 7;
    int chunk = blockIdx.x >> 3;
    int e = chunk * 256 + threadIdx.x;
    int r = row[e];
    unsigned int rel = (unsigned int)(r - seg * SEG_SIZE);
    if (rel < (unsigned int)SEG_SIZE) {
        unsigned int p = offs[r] + (unsigned int)rank[e];
        sorted_c[p] = col[e];
    }
}

// ---------- row aggregate ----------
__global__ __launch_bounds__(256) void row_kernel(const uint2* __restrict__ seqb2,
                                                  const int* __restrict__ sorted_c,
                                                  const unsigned int* __restrict__ offs,
                                                  const unsigned int* __restrict__ cnt,
                                                  const float* __restrict__ f1,
                                                  const float* __restrict__ f2,
                                                  const float* __restrict__ bias,
                                                  float* __restrict__ out) {
    int wid  = (blockIdx.x * 256 + threadIdx.x) >> 6;   // row
    int lane = threadIdx.x & 63;
    int half = lane >> 5;
    int j2   = lane & 31;       // cols 4*j2 .. 4*j2+3
    if (wid >= N_NODES) return;
    unsigned int start = offs[wid];
    unsigned int deg   = cnt[wid];
    const int* sc = sorted_c + start;
    float f1r = f1[wid];

    float a0 = 0.f, a1 = 0.f, a2 = 0.f, a3 = 0.f, ss = 0.f;
    unsigned int k = 0;
    for (; k + 8 <= deg; k += 8) {
        int c0 = sc[k + 0 + half];
        int c1 = sc[k + 2 + half];
        int c2 = sc[k + 4 + half];
        int c3 = sc[k + 6 + half];
        uint2 v0 = seqb2[(size_t)c0 * 32 + j2];
        uint2 v1 = seqb2[(size_t)c1 * 32 + j2];
        uint2 v2 = seqb2[(size_t)c2 * 32 + j2];
        uint2 v3 = seqb2[(size_t)c3 * 32 + j2];
        float t0 = f1r + f2[c0], t1 = f1r + f2[c1];
        float t2 = f1r + f2[c2], t3 = f1r + f2[c3];
        float w0 = __expf(t0 > 0.f ? t0 : ALPHA * t0);
        float w1 = __expf(t1 > 0.f ? t1 : ALPHA * t1);
        float w2 = __expf(t2 > 0.f ? t2 : ALPHA * t2);
        float w3 = __expf(t3 > 0.f ? t3 : ALPHA * t3);
        a0 += w0 * bflo(v0.x); a1 += w0 * bfhi(v0.x); a2 += w0 * bflo(v0.y); a3 += w0 * bfhi(v0.y);
        a0 += w1 * bflo(v1.x); a1 += w1 * bfhi(v1.x); a2 += w1 * bflo(v1.y); a3 += w1 * bfhi(v1.y);
        a0 += w2 * bflo(v2.x); a1 += w2 * bfhi(v2.x); a2 += w2 * bflo(v2.y); a3 += w2 * bfhi(v2.y);
        a0 += w3 * bflo(v3.x); a1 += w3 * bfhi(v3.x); a2 += w3 * bflo(v3.y); a3 += w3 * bfhi(v3.y);
        ss += w0 + w1 + w2 + w3;
    }
    for (; k + 2 <= deg; k += 2) {       // pairs: one edge per half
        int c0 = sc[k + half];
        uint2 v0 = seqb2[(size_t)c0 * 32 + j2];
        float t0 = f1r + f2[c0];
        float w0 = __expf(t0 > 0.f ? t0 : ALPHA * t0);
        a0 += w0 * bflo(v0.x); a1 += w0 * bfhi(v0.x); a2 += w0 * bflo(v0.y); a3 += w0 * bfhi(v0.y);
        ss += w0;
    }
    if (k < deg && half == 0) {          // final odd edge: half 0 only
        int c0 = sc[k];
        uint2 v0 = seqb2[(size_t)c0 * 32 + j2];
        float t0 = f1r + f2[c0];
        float w0 = __expf(t0 > 0.f ? t0 : ALPHA * t0);
        a0 += w0 * bflo(v0.x); a1 += w0 * bfhi(v0.x); a2 += w0 * bflo(v0.y); a3 += w0 * bfhi(v0.y);
        ss += w0;
    }
    a0 += __shfl_xor(a0, 32);
    a1 += __shfl_xor(a1, 32);
    a2 += __shfl_xor(a2, 32);
    a3 += __shfl_xor(a3, 32);
    ss += __shfl_xor(ss, 32);

    if (half == 0) {
        float inv = (deg > 0) ? 1.f / ss : 0.f;   // empty row -> bias only
        float4 b4 = ((const float4*)bias)[j2];
        ((float4*)(out + (size_t)wid * D_OUT))[j2] =
            make_float4(a0 * inv + b4.x, a1 * inv + b4.y, a2 * inv + b4.z, a3 * inv + b4.w);
    }
}

extern "C" void kernel_launch(void* const* d_in, const int* in_sizes, int n_in,
                              void* d_out, int out_size, void* d_ws, size_t ws_size,
                              hipStream_t stream) {
    const float* feat = (const float*)d_in[0];
    const int*   row  = (const int*)d_in[1];
    const int*   col  = (const int*)d_in[2];
    const float* W    = (const float*)d_in[3];
    const float* al_w = (const float*)d_in[4];
    const float* al_b = (const float*)d_in[5];
    const float* ar_w = (const float*)d_in[6];
    const float* ar_b = (const float*)d_in[7];
    const float* bias = (const float*)d_in[8];
    float* out = (float*)d_out;

    char* ws = (char*)d_ws;
    size_t off = 0;
    auto carve = [&](size_t bytes) -> void* {
        off = (off + 255) & ~(size_t)255;
        void* p = ws + off;
        off += bytes;
        return p;
    };
    unsigned int* seqb     = (unsigned int*)carve((size_t)N_NODES * 64 * 4);  // bf16x2 packed
    float*        f1       = (float*)       carve((size_t)N_NODES * 4);
    float*        f2       = (float*)       carve((size_t)N_NODES * 4);
    unsigned int* cnt      = (unsigned int*)carve((size_t)N_NODES * 4);
    unsigned int* offs     = (unsigned int*)carve((size_t)N_NODES * 4);
    unsigned int* bsums    = (unsigned int*)carve(1024 * 4);
    unsigned int* bexcl    = (unsigned int*)carve(1024 * 4);
    short*        WT       = (short*)       carve((size_t)D_IN * D_OUT * 2);  // bf16 W^T
    unsigned char* rank    = (unsigned char*)carve((size_t)N_EDGES);
    int*          sorted_c = (int*)         carve((size_t)N_EDGES * 4);
    (void)ws_size; (void)in_sizes; (void)n_in; (void)out_size;

    const int nb_nodes = (N_NODES + 255) / 256;     // 391
    const int nb_gemm  = (N_NODES + 63) / 64;       // 1563 (last block guarded)
    const int nb_e4    = (N_EDGES / 4) / 256;       // 3125 exact
    const int nb_scat  = (N_EDGES / 256) * NSEG;    // 100000
    const int nb_row   = N_NODES / 4;               // 25000 exact (4 waves/block)

    init_kernel<<<nb_nodes, 256, 0, stream>>>(cnt);
    wt_kernel<<<(D_IN * D_OUT) / 256, 256, 0, stream>>>(W, WT);
    gemm_kernel<<<nb_gemm, 256, 0, stream>>>(feat, WT, al_w, al_b, ar_w, ar_b, seqb, f1, f2);
    hist_rank<<<nb_e4, 256, 0, stream>>>((const int4*)row, cnt, (uchar4*)rank);
    scan1<<<nb_nodes, 256, 0, stream>>>(cnt, offs, bsums);
    scan2<<<1, 512, 0, stream>>>(bsums, bexcl, nb_nodes);
    scan3<<<nb_nodes, 256, 0, stream>>>(offs, bexcl);
    scatter_kernel<<<nb_scat, 256, 0, stream>>>(row, col, rank, offs, sorted_c);
    row_kernel<<<nb_row, 256, 0, stream>>>((const uint2*)seqb, sorted_c, offs, cnt, f1, f2, bias, out);
}